// Round 1
// baseline (1142.407 us; speedup 1.0000x reference)
//
#include <hip/hip_runtime.h>
#include <hip/hip_bf16.h>
#include <stdint.h>

// Problem: out[M,N] = x[M,K] @ W'[N,K]^T + bias[N], where W' = W + SCALE*(loraB @ loraA)
// M = 16384 (B*S), N = 4096, K = 4096. SCALE = 16/16 = 1.0.
#define M_DIM 16384
#define N_DIM 4096
#define K_DIM 4096
#define LORA_SCALE 1.0f

typedef _Float16 half8 __attribute__((ext_vector_type(8)));
typedef float f32x4 __attribute__((ext_vector_type(4)));

// ---------------------------------------------------------------------------
// Kernel 1: convert x (fp32) -> f16, 8 elements/thread, fully vectorized.
// ---------------------------------------------------------------------------
__global__ __launch_bounds__(256) void cvt_x_kernel(const float* __restrict__ x,
                                                    _Float16* __restrict__ xb) {
    size_t base = ((size_t)blockIdx.x * 256 + (size_t)threadIdx.x) * 8;
    f32x4 a = *(const f32x4*)(x + base);
    f32x4 b = *(const f32x4*)(x + base + 4);
    half8 h;
    h[0] = (_Float16)a[0]; h[1] = (_Float16)a[1];
    h[2] = (_Float16)a[2]; h[3] = (_Float16)a[3];
    h[4] = (_Float16)b[0]; h[5] = (_Float16)b[1];
    h[6] = (_Float16)b[2]; h[7] = (_Float16)b[3];
    *(half8*)(xb + base) = h;
}

// ---------------------------------------------------------------------------
// Kernel 2: W'[n,k] = W[n,k] + SCALE * sum_r loraB[n,r]*loraA[r,k]  -> f16.
// One block handles 16 rows of W'. A is staged per-256-column chunk in LDS.
// ---------------------------------------------------------------------------
__global__ __launch_bounds__(256) void prep_w_kernel(const float* __restrict__ W,
                                                     const float* __restrict__ lA,
                                                     const float* __restrict__ lB,
                                                     _Float16* __restrict__ wp) {
    __shared__ float A_lds[16][256];
    __shared__ float B_lds[256];
    const int t = threadIdx.x;
    const int n0 = blockIdx.x * 16;

    // loraB is [N,16] row-major: rows n0..n0+15 are 256 contiguous floats.
    B_lds[t] = lB[(size_t)n0 * 16 + t];

    for (int kc = 0; kc < 16; ++kc) {
        const int k = kc * 256 + t;
        __syncthreads();  // prev compute done before overwrite (and B_lds visible)
#pragma unroll
        for (int r = 0; r < 16; ++r) A_lds[r][t] = lA[(size_t)r * K_DIM + k];
        __syncthreads();
#pragma unroll 4
        for (int row = 0; row < 16; ++row) {
            float acc = W[(size_t)(n0 + row) * K_DIM + k];
            float dot = 0.f;
#pragma unroll
            for (int r = 0; r < 16; ++r) dot += B_lds[row * 16 + r] * A_lds[r][t];
            acc += LORA_SCALE * dot;
            wp[(size_t)(n0 + row) * K_DIM + k] = (_Float16)acc;
        }
    }
}

// ---------------------------------------------------------------------------
// Kernel 3: m97-structure GEMM. C[m,n] = sum_k A[m,k]*B[n,k] + bias[n].
// 128x128 block tile, BK=32, 4 waves in 2x2, each wave = 4x4 of 16x16x32 MFMA.
// Staging via global_load_lds width=16 (wave-uniform LDS base + lane*16).
// ---------------------------------------------------------------------------
__device__ inline void load_lds16(const void* g, void* l) {
    __builtin_amdgcn_global_load_lds(
        (const __attribute__((address_space(1))) unsigned int*)(uintptr_t)g,
        (__attribute__((address_space(3))) unsigned int*)(uintptr_t)l,
        16, 0, 0);
}

__global__ __launch_bounds__(256) void gemm_bt_kernel(const _Float16* __restrict__ A,
                                                      const _Float16* __restrict__ B,
                                                      const float* __restrict__ bias,
                                                      float* __restrict__ C) {
    // Unpadded: layout must be lane-contiguous for global_load_lds.
    __shared__ _Float16 As[128 * 32];
    __shared__ _Float16 Bs[128 * 32];

    const int tid  = threadIdx.x;
    const int lane = tid & 63;
    const int wave = tid >> 6;
    const int quad = lane >> 4;   // 0..3 -> k-slice of fragment / row-group of C
    const int r16  = lane & 15;   // row within 16-tile (A: m, B: n, C: col n)
    const int wm   = wave >> 1;   // 0..1
    const int wn   = wave & 1;    // 0..1

    const int m0 = blockIdx.y * 128;
    const int n0 = blockIdx.x * 128;

    // Chunk c in [0,512): 8 f16 elements = 16 B. row = c>>2, col8 = c&3.
    // LDS element offset of chunk c is exactly c*8 (row-major [128][32]).
    const int c0 = tid;        // chunks 0..255   (rows 0..63)
    const int c1 = tid + 256;  // chunks 256..511 (rows 64..127)

    const _Float16* gA0 = A + (size_t)(m0 + (c0 >> 2)) * K_DIM + ((c0 & 3) << 3);
    const _Float16* gA1 = A + (size_t)(m0 + (c1 >> 2)) * K_DIM + ((c1 & 3) << 3);
    const _Float16* gB0 = B + (size_t)(n0 + (c0 >> 2)) * K_DIM + ((c0 & 3) << 3);
    const _Float16* gB1 = B + (size_t)(n0 + (c1 >> 2)) * K_DIM + ((c1 & 3) << 3);
    _Float16* lA0 = &As[c0 * 8];
    _Float16* lA1 = &As[c1 * 8];
    _Float16* lB0 = &Bs[c0 * 8];
    _Float16* lB1 = &Bs[c1 * 8];

    f32x4 acc[4][4] = {};

    for (int kt = 0; kt < K_DIM / 32; ++kt) {
        load_lds16(gA0, lA0);
        load_lds16(gA1, lA1);
        load_lds16(gB0, lB0);
        load_lds16(gB1, lB1);
        gA0 += 32; gA1 += 32; gB0 += 32; gB1 += 32;

        __syncthreads();  // drains vmcnt: LDS tiles visible

        half8 af[4], bf[4];
#pragma unroll
        for (int i = 0; i < 4; ++i)
            af[i] = *(const half8*)&As[(wm * 64 + i * 16 + r16) * 32 + quad * 8];
#pragma unroll
        for (int j = 0; j < 4; ++j)
            bf[j] = *(const half8*)&Bs[(wn * 64 + j * 16 + r16) * 32 + quad * 8];

#pragma unroll
        for (int i = 0; i < 4; ++i)
#pragma unroll
            for (int j = 0; j < 4; ++j)
                acc[i][j] = __builtin_amdgcn_mfma_f32_16x16x32_f16(af[i], bf[j],
                                                                   acc[i][j], 0, 0, 0);

        __syncthreads();  // all reads done before next overwrite
    }

    // Epilogue: C/D layout col = lane&15, row = quad*4 + reg.
#pragma unroll
    for (int j = 0; j < 4; ++j) {
        const int n = n0 + wn * 64 + j * 16 + r16;
        const float bv = bias[n];
#pragma unroll
        for (int i = 0; i < 4; ++i) {
            const int mbase = m0 + wm * 64 + i * 16 + quad * 4;
#pragma unroll
            for (int r = 0; r < 4; ++r) {
                C[(size_t)(mbase + r) * N_DIM + n] = acc[i][j][r] + bv;
            }
        }
    }
}

// ---------------------------------------------------------------------------
extern "C" void kernel_launch(void* const* d_in, const int* in_sizes, int n_in,
                              void* d_out, int out_size, void* d_ws, size_t ws_size,
                              hipStream_t stream) {
    const float* x      = (const float*)d_in[0];  // [4,4096,4096] fp32 -> [M,K]
    const float* weight = (const float*)d_in[1];  // [N,K] fp32
    const float* bias   = (const float*)d_in[2];  // [N] fp32
    const float* lora_A = (const float*)d_in[3];  // [16,K] fp32
    const float* lora_B = (const float*)d_in[4];  // [N,16] fp32
    float* out = (float*)d_out;

    _Float16* xb = (_Float16*)d_ws;                                   // 128 MiB
    _Float16* wp = (_Float16*)((char*)d_ws + (size_t)M_DIM * K_DIM * 2);  // +32 MiB

    // 1) x -> f16
    cvt_x_kernel<<<dim3((M_DIM * (size_t)K_DIM) / (256 * 8)), dim3(256), 0, stream>>>(x, xb);
    // 2) W' = W + loraB@loraA -> f16
    prep_w_kernel<<<dim3(N_DIM / 16), dim3(256), 0, stream>>>(weight, lora_A, lora_B, wp);
    // 3) GEMM + bias
    gemm_bt_kernel<<<dim3(N_DIM / 128, M_DIM / 128), dim3(256), 0, stream>>>(xb, wp, bias, out);
}